// Round 12
// baseline (58.487 us; speedup 1.0000x reference)
//
#include <hip/hip_runtime.h>

typedef __attribute__((ext_vector_type(8))) short bf16x8;
typedef __attribute__((ext_vector_type(8))) unsigned short ushort8;
typedef __attribute__((ext_vector_type(4))) float f32x4;

static __device__ __forceinline__ unsigned short f2bf(float f) {
  union { float f; unsigned u; } v; v.f = f;
  unsigned r = v.u + 0x7FFFu + ((v.u >> 16) & 1u);
  return (unsigned short)(r >> 16);
}
static __device__ __forceinline__ int iclamp(int x, int lo, int hi) {
  return x < lo ? lo : (x > hi ? hi : x);
}
// async global->LDS, 16B per lane; LDS dest = wave-uniform base + lane*16
static __device__ __forceinline__ void gl_lds16(const unsigned short* g,
                                                unsigned short* l) {
  __builtin_amdgcn_global_load_lds(
      (const __attribute__((address_space(1))) void*)g,
      (__attribute__((address_space(3))) void*)l, 16, 0, 0);
}

// ---------------- fused fp32 -> bf16 converts (one launch) ----------------
__global__ void cvt_all(const float* __restrict__ x,
                        const float* __restrict__ w_in,
                        const float* __restrict__ w_out,
                        unsigned short* __restrict__ xb,
                        unsigned short* __restrict__ wbin,
                        unsigned short* __restrict__ wbo) {
  const int NX4 = 1048576, NWI4 = 196608, NWO4 = 65536;  // float4 counts
  const int total = NX4 + NWI4 + NWO4;
  for (int i = blockIdx.x * blockDim.x + threadIdx.x; i < total;
       i += gridDim.x * blockDim.x) {
    const float* src;
    unsigned short* dst;
    int o;
    if (i < NX4) {
      src = x; dst = xb; o = i;
    } else if (i < NX4 + NWI4) {
      src = w_in; dst = wbin; o = i - NX4;
    } else {
      src = w_out; dst = wbo; o = i - NX4 - NWI4;
    }
    float4 v = reinterpret_cast<const float4*>(src)[o];
    ushort4 u;
    u.x = f2bf(v.x); u.y = f2bf(v.y); u.z = f2bf(v.z); u.w = f2bf(v.w);
    reinterpret_cast<ushort4*>(dst)[o] = u;
  }
}

// ------- GEMM1, 8-phase 256x256: C(bf16) = A[M][K] * B[N][K]^T + bias -------
// 8 waves (2M x 4N), per-wave 128x64. BK=64 split in column halves (kh).
// LDS: As/Bs[2 dbuf][2 kh][256 rows][32 elems] = 128 KiB.
// Swizzle (T2/T21 both-sides): LDS[row][c] = G[row][c ^ (row&3) ^ ((row>>2)&3)]
//   (c = 16B chunk). gl_lds: lane l of instr j covers row base+(l>>2), chunk
//   l&3, so source chunk = (l&3)^((l>>2)&3)^((l>>4)&3). Reads XOR same key.
// Phases per K-tile t: p0 {stage A-kh0(t+1); vmcnt(6); BAR; read+16 MFMA kh0 mi0-3}
//                      p1 {stage B-kh0(t+1); read+MFMA kh0 mi4-7 (reuse B frags)}
//                      p2 {stage A-kh1(t+1); vmcnt(6); BAR; read+MFMA kh1 mi0-3}
//                      p3 {stage B-kh1(t+1); read+MFMA kh1 mi4-7}; BAR at loop top.
// vmcnt ledger (per wave, 2 loads/stage): at p0 wait: outstanding =
//   prev-iter {A0,B0,A1,B1}=8 + own A0=2 = 10 -> vmcnt(6) completes oldest 4 =
//   prev A0+B0 = exactly this iter's kh0 data; then BAR makes ALL waves'
//   stages visible before any read. p2: +4 issued -> vmcnt(6) completes prev
//   A1+B1. Last iter (no stages): vmcnt(4) / vmcnt(0). Never drains pipeline.
__global__ __launch_bounds__(512) void gemm8p(
    const unsigned short* __restrict__ A, const unsigned short* __restrict__ B,
    const float* __restrict__ bias, unsigned short* __restrict__ C,
    int M, int N, int K) {
  __shared__ unsigned short As[2][2][256][32];  // 64 KiB
  __shared__ unsigned short Bs[2][2][256][32];  // 64 KiB
  const int tid = threadIdx.x;
  const int lane = tid & 63;
  const int wid = tid >> 6;  // 0..7

  // XCD-aware bijective swizzle (nwg = 192, multiple of 8)
  const int nwg = gridDim.x * gridDim.y;
  const int orig = blockIdx.y * gridDim.x + blockIdx.x;
  const int q = nwg >> 3, r = nwg & 7;
  const int xcd = orig & 7, lid = orig >> 3;
  const int swz = (xcd < r ? xcd * (q + 1) : r * (q + 1) + (xcd - r) * q) + lid;
  const int bm = (swz / gridDim.x) * 256;
  const int bn = (swz % gridDim.x) * 256;

  const int wr = (wid >> 2) * 128;  // wave M offset
  const int wc = (wid & 3) * 64;    // wave N offset
  const int row16 = lane & 15;
  const int kgrp = lane >> 4;
  const int rch = kgrp ^ (row16 & 3) ^ ((row16 >> 2) & 3);  // read chunk

  // staging: wave w instr j covers rows w*32 + j*16 .. +15 (16 rows x 64B)
  const int srow = wid * 32 + (lane >> 2);
  const int csrc = (lane & 3) ^ ((lane >> 2) & 3) ^ ((lane >> 4) & 3);
  const unsigned short* gA = A + (size_t)(bm + srow) * K + csrc * 8;
  const unsigned short* gB = B + (size_t)(bn + srow) * K + csrc * 8;
  const size_t K16 = (size_t)16 * K;

#define SA(buf, kh, kt)                                               \
  {                                                                   \
    gl_lds16(gA + (kt) * 64 + (kh) * 32, &As[buf][kh][wid * 32][0]);  \
    gl_lds16(gA + K16 + (kt) * 64 + (kh) * 32,                        \
             &As[buf][kh][wid * 32 + 16][0]);                         \
  }
#define SB(buf, kh, kt)                                               \
  {                                                                   \
    gl_lds16(gB + (kt) * 64 + (kh) * 32, &Bs[buf][kh][wid * 32][0]);  \
    gl_lds16(gB + K16 + (kt) * 64 + (kh) * 32,                        \
             &Bs[buf][kh][wid * 32 + 16][0]);                         \
  }

  f32x4 acc[8][4] = {};

  // prologue: tile 0 -> buf 0 (order A0, B0, A1, B1)
  SA(0, 0, 0); SB(0, 0, 0); SA(0, 1, 0); SB(0, 1, 0);

  const int NT = K >> 6;  // 8
  for (int t = 0; t < NT; ++t) {
    const int cur = t & 1;
    const int nxt = cur ^ 1;
    const bool st = (t + 1 < NT);
    __builtin_amdgcn_s_barrier();  // end of prev iter: all reads of buf[nxt] done
    bf16x8 af[4], bfr[4];
    // ---------- phase 0: kh=0, mi 0..3 ----------
    if (st) { SA(nxt, 0, t + 1); }
    if (st) asm volatile("s_waitcnt vmcnt(6)" ::: "memory");
    else    asm volatile("s_waitcnt vmcnt(4)" ::: "memory");
    __builtin_amdgcn_s_barrier();  // kh0 data (A+B) visible to all waves
#pragma unroll
    for (int mi = 0; mi < 4; ++mi)
      af[mi] = *reinterpret_cast<const bf16x8*>(
          &As[cur][0][wr + mi * 16 + row16][rch * 8]);
#pragma unroll
    for (int ni = 0; ni < 4; ++ni)
      bfr[ni] = *reinterpret_cast<const bf16x8*>(
          &Bs[cur][0][wc + ni * 16 + row16][rch * 8]);
    __builtin_amdgcn_s_setprio(1);
#pragma unroll
    for (int mi = 0; mi < 4; ++mi)
#pragma unroll
      for (int ni = 0; ni < 4; ++ni)
        acc[mi][ni] = __builtin_amdgcn_mfma_f32_16x16x32_bf16(
            af[mi], bfr[ni], acc[mi][ni], 0, 0, 0);
    __builtin_amdgcn_s_setprio(0);
    // ---------- phase 1: kh=0, mi 4..7 (reuse bfr) ----------
    if (st) { SB(nxt, 0, t + 1); }
#pragma unroll
    for (int mi = 0; mi < 4; ++mi)
      af[mi] = *reinterpret_cast<const bf16x8*>(
          &As[cur][0][wr + 64 + mi * 16 + row16][rch * 8]);
    __builtin_amdgcn_s_setprio(1);
#pragma unroll
    for (int mi = 0; mi < 4; ++mi)
#pragma unroll
      for (int ni = 0; ni < 4; ++ni)
        acc[4 + mi][ni] = __builtin_amdgcn_mfma_f32_16x16x32_bf16(
            af[mi], bfr[ni], acc[4 + mi][ni], 0, 0, 0);
    __builtin_amdgcn_s_setprio(0);
    // ---------- phase 2: kh=1, mi 0..3 ----------
    if (st) { SA(nxt, 1, t + 1); }
    if (st) asm volatile("s_waitcnt vmcnt(6)" ::: "memory");
    else    asm volatile("s_waitcnt vmcnt(0)" ::: "memory");
    __builtin_amdgcn_s_barrier();  // kh1 data visible
#pragma unroll
    for (int mi = 0; mi < 4; ++mi)
      af[mi] = *reinterpret_cast<const bf16x8*>(
          &As[cur][1][wr + mi * 16 + row16][rch * 8]);
#pragma unroll
    for (int ni = 0; ni < 4; ++ni)
      bfr[ni] = *reinterpret_cast<const bf16x8*>(
          &Bs[cur][1][wc + ni * 16 + row16][rch * 8]);
    __builtin_amdgcn_s_setprio(1);
#pragma unroll
    for (int mi = 0; mi < 4; ++mi)
#pragma unroll
      for (int ni = 0; ni < 4; ++ni)
        acc[mi][ni] = __builtin_amdgcn_mfma_f32_16x16x32_bf16(
            af[mi], bfr[ni], acc[mi][ni], 0, 0, 0);
    __builtin_amdgcn_s_setprio(0);
    // ---------- phase 3: kh=1, mi 4..7 ----------
    if (st) { SB(nxt, 1, t + 1); }
#pragma unroll
    for (int mi = 0; mi < 4; ++mi)
      af[mi] = *reinterpret_cast<const bf16x8*>(
          &As[cur][1][wr + 64 + mi * 16 + row16][rch * 8]);
    __builtin_amdgcn_s_setprio(1);
#pragma unroll
    for (int mi = 0; mi < 4; ++mi)
#pragma unroll
      for (int ni = 0; ni < 4; ++ni)
        acc[4 + mi][ni] = __builtin_amdgcn_mfma_f32_16x16x32_bf16(
            af[mi], bfr[ni], acc[4 + mi][ni], 0, 0, 0);
    __builtin_amdgcn_s_setprio(0);
  }
#undef SA
#undef SB

  // epilogue: bias + bf16 store, row-major C
#pragma unroll
  for (int ni = 0; ni < 4; ++ni) {
    const int gcol = bn + wc + ni * 16 + row16;
    const float bv = bias[gcol];
#pragma unroll
    for (int mi = 0; mi < 8; ++mi) {
#pragma unroll
      for (int r2 = 0; r2 < 4; ++r2) {
        const int grow = bm + wr + mi * 16 + kgrp * 4 + r2;
        C[(size_t)grow * N + gcol] = f2bf(acc[mi][ni][r2] + bv);
      }
    }
  }
}

// ------- GEMM2: C[M][N](fp32) = A[M][K](bf16) * B[N][K]^T + bias -------
// (round-6/10 structure: BK=64 dbuf, gl_lds pre-swizzled source, 2-phase)
template <int BM, int BN, int WM, int WN>
__global__ __launch_bounds__(256) void gemm_bt(
    const unsigned short* __restrict__ A, const unsigned short* __restrict__ B,
    const float* __restrict__ bias, float* __restrict__ Cv,
    int M, int N, int K) {
  __shared__ unsigned short As[2][BM][64];
  __shared__ unsigned short Bs[2][BN][64];
  const int tid = threadIdx.x;
  const int lane = tid & 63;
  const int wid = tid >> 6;

  const int nwg = gridDim.x * gridDim.y;
  const int orig = blockIdx.y * gridDim.x + blockIdx.x;
  const int q = nwg >> 3, r = nwg & 7;
  const int xcd = orig & 7, lid = orig >> 3;
  const int swz = (xcd < r ? xcd * (q + 1) : r * (q + 1) + (xcd - r) * q) + lid;
  const int bm = (swz / gridDim.x) * BM;
  const int bn = (swz % gridDim.x) * BN;

  const int NWC = BN / WN;
  const int wr = (wid / NWC) * WM;
  const int wc = (wid % NWC) * WN;
  const int row16 = lane & 15;
  const int kgrp = lane >> 4;
  const int rsw = row16 & 7;

  const int srA = wid * (BM / 4) + (lane >> 3);
  const int srB = wid * (BN / 4) + (lane >> 3);
  const int schunk = ((lane & 7) ^ (lane >> 3)) * 8;
  const unsigned short* gA = A + (size_t)(bm + srA) * K + schunk;
  const unsigned short* gB = B + (size_t)(bn + srB) * K + schunk;
  const size_t K8 = (size_t)8 * K;

#define STAGE(buf, k0)                                                   \
  {                                                                      \
    _Pragma("unroll") for (int j = 0; j < BM / 32; ++j)                  \
        gl_lds16(gA + j * K8 + (k0), &As[buf][wid * (BM / 4) + j * 8][0]); \
    _Pragma("unroll") for (int j = 0; j < BN / 32; ++j)                  \
        gl_lds16(gB + j * K8 + (k0), &Bs[buf][wid * (BN / 4) + j * 8][0]); \
  }

  f32x4 acc[WM / 16][WN / 16] = {};

  STAGE(0, 0);
  asm volatile("s_waitcnt vmcnt(0)" ::: "memory");
  __builtin_amdgcn_s_barrier();

  const int NT = K >> 6;
  for (int t = 0; t < NT; ++t) {
    const int cur = t & 1;
    if (t + 1 < NT) STAGE(cur ^ 1, (t + 1) * 64);
    bf16x8 af[WM / 16][2], bfr[WN / 16][2];
#pragma unroll
    for (int mi = 0; mi < WM / 16; ++mi)
#pragma unroll
      for (int kh = 0; kh < 2; ++kh)
        af[mi][kh] = *reinterpret_cast<const bf16x8*>(
            &As[cur][wr + mi * 16 + row16][((kh * 4 + kgrp) ^ rsw) * 8]);
#pragma unroll
    for (int ni = 0; ni < WN / 16; ++ni)
#pragma unroll
      for (int kh = 0; kh < 2; ++kh)
        bfr[ni][kh] = *reinterpret_cast<const bf16x8*>(
            &Bs[cur][wc + ni * 16 + row16][((kh * 4 + kgrp) ^ rsw) * 8]);
#pragma unroll
    for (int kh = 0; kh < 2; ++kh)
#pragma unroll
      for (int mi = 0; mi < WM / 16; ++mi)
#pragma unroll
        for (int ni = 0; ni < WN / 16; ++ni)
          acc[mi][ni] = __builtin_amdgcn_mfma_f32_16x16x32_bf16(
              af[mi][kh], bfr[ni][kh], acc[mi][ni], 0, 0, 0);
    asm volatile("s_waitcnt vmcnt(0)" ::: "memory");
    __builtin_amdgcn_s_barrier();
  }
#undef STAGE

#pragma unroll
  for (int ni = 0; ni < WN / 16; ++ni) {
    const int gcol = bn + wc + ni * 16 + row16;
    const float bv = bias[gcol];
#pragma unroll
    for (int mi = 0; mi < WM / 16; ++mi) {
#pragma unroll
      for (int r2 = 0; r2 < 4; ++r2) {
        const int grow = bm + wr + mi * 16 + kgrp * 4 + r2;
        Cv[(size_t)grow * N + gcol] = acc[mi][ni][r2] + bv;
      }
    }
  }
}

// ---------------- local (banded) attention, v3 + XCD-chunked grid ----------------
__global__ __launch_bounds__(256) void attn_local(
    const unsigned short* __restrict__ qkv, unsigned short* __restrict__ ctx,
    int S) {
  __shared__ unsigned Vt[64][76];            // 19456 B
  __shared__ unsigned short Ps[4][16][104];  // 13312 B

  const int tid = threadIdx.x;
  const int lane = tid & 63;
  const int wid = tid >> 6;

  // bijective XCD-chunked swizzle: nwg = (S/64)*16, multiple of 8
  const int nqb = S >> 6;
  const int nwg = nqb * 16;
  const int orig = blockIdx.y * gridDim.x + blockIdx.x;
  const int cpx = nwg >> 3;
  const int swzb = (orig & 7) * cpx + (orig >> 3);
  const int q0 = (swzb % nqb) * 64;
  const int bh = swzb / nqb;
  const int b = bh >> 3;
  const int h = bh & 7;

  const int row16 = lane & 15;
  const int kgrp = lane >> 4;
  const size_t bS = (size_t)b * S;

  // ---- stage V transposed (packed key pairs) ----
  {
    const int k2 = tid >> 2;
    const int dq = (tid & 3) * 16;
    const int ra = iclamp(q0 - 32 + 2 * k2, 0, S - 1);
    const int rb = iclamp(q0 - 32 + 2 * k2 + 1, 0, S - 1);
    const unsigned short* pa = qkv + (bS + ra) * 1536 + 1024 + h * 64 + dq;
    const unsigned short* pb = qkv + (bS + rb) * 1536 + 1024 + h * 64 + dq;
    ushort8 a0 = reinterpret_cast<const ushort8*>(pa)[0];
    ushort8 a1 = reinterpret_cast<const ushort8*>(pa)[1];
    ushort8 b0 = reinterpret_cast<const ushort8*>(pb)[0];
    ushort8 b1 = reinterpret_cast<const ushort8*>(pb)[1];
#pragma unroll
    for (int d = 0; d < 8; ++d) {
      Vt[dq + d][k2] = (unsigned)a0[d] | ((unsigned)b0[d] << 16);
      Vt[dq + 8 + d][k2] = (unsigned)a1[d] | ((unsigned)b1[d] << 16);
    }
    const int zr = tid >> 2;
    const int zc = 64 + (tid & 3) * 2;
    Vt[zr][zc] = 0u;
    Vt[zr][zc + 1] = 0u;
  }

  // ---- Q fragments (direct from global) ----
  bf16x8 qf0, qf1;
  {
    const unsigned short* qp =
        qkv + (bS + q0 + wid * 16 + row16) * 1536 + h * 64;
    qf0 = *reinterpret_cast<const bf16x8*>(qp + kgrp * 8);
    qf1 = *reinterpret_cast<const bf16x8*>(qp + 32 + kgrp * 8);
  }

  // ---- QK^T: 5 key tiles, K direct from global (clamped rows) ----
  f32x4 sc[5];
#pragma unroll
  for (int t = 0; t < 5; ++t) {
    const int key = iclamp(q0 - 32 + (wid + t) * 16 + row16, 0, S - 1);
    const unsigned short* kp = qkv + (bS + key) * 1536 + 512 + h * 64;
    bf16x8 kf0 = *reinterpret_cast<const bf16x8*>(kp + kgrp * 8);
    bf16x8 kf1 = *reinterpret_cast<const bf16x8*>(kp + 32 + kgrp * 8);
    f32x4 s = {0.f, 0.f, 0.f, 0.f};
    s = __builtin_amdgcn_mfma_f32_16x16x32_bf16(qf0, kf0, s, 0, 0, 0);
    s = __builtin_amdgcn_mfma_f32_16x16x32_bf16(qf1, kf1, s, 0, 0, 0);
    sc[t] = s;
  }

  // ---- mask + softmax ----
  const int ccol = row16;
  const int crow4 = kgrp * 4;
  float rm[4] = {-INFINITY, -INFINITY, -INFINITY, -INFINITY};
#pragma unroll
  for (int t = 0; t < 5; ++t)
#pragma unroll
    for (int r = 0; r < 4; ++r) {
      const int key_abs = q0 - 32 + (wid + t) * 16 + ccol;
      const int diff = -32 + t * 16 + ccol - crow4 - r;
      float s = sc[t][r] * 0.125f;
      const bool valid =
          (diff >= -32) && (diff <= 32) && (key_abs >= 0) && (key_abs < S);
      s = valid ? s : -INFINITY;
      sc[t][r] = s;
      rm[r] = fmaxf(rm[r], s);
    }
#pragma unroll
  for (int off = 1; off < 16; off <<= 1)
#pragma unroll
    for (int r = 0; r < 4; ++r) rm[r] = fmaxf(rm[r], __shfl_xor(rm[r], off, 64));
  float rs[4] = {0.f, 0.f, 0.f, 0.f};
#pragma unroll
  for (int t = 0; t < 5; ++t)
#pragma unroll
    for (int r = 0; r < 4; ++r) {
      const float p = __expf(sc[t][r] - rm[r]);
      sc[t][r] = p;
      rs[r] += p;
    }
#pragma unroll
  for (int off = 1; off < 16; off <<= 1)
#pragma unroll
    for (int r = 0; r < 4; ++r) rs[r] += __shfl_xor(rs[r], off, 64);

  // ---- P -> LDS (bf16), zero-pad keys 80..95 ----
#pragma unroll
  for (int t = 0; t < 5; ++t)
#pragma unroll
    for (int r = 0; r < 4; ++r)
      Ps[wid][crow4 + r][t * 16 + ccol] = f2bf(sc[t][r]);
#pragma unroll
  for (int j = 0; j < 4; ++j) Ps[wid][row16][80 + kgrp * 4 + j] = 0;

  __syncthreads();

  // ---- PV: ctx[16x64] = P[16x96] * V[96x64] ----
  f32x4 cacc[4] = {};
#pragma unroll
  for (int kc = 0; kc < 3; ++kc) {
    bf16x8 pf = *reinterpret_cast<const bf16x8*>(&Ps[wid][row16][kc * 32 + kgrp * 8]);
#pragma unroll
    for (int ni = 0; ni < 4; ++ni) {
      bf16x8 vf = *reinterpret_cast<const bf16x8*>(
          &Vt[ni * 16 + row16][wid * 8 + kc * 16 + kgrp * 4]);
      cacc[ni] = __builtin_amdgcn_mfma_f32_16x16x32_bf16(pf, vf, cacc[ni], 0, 0, 0);
    }
  }

  // ---- normalize + store ----
  float inv[4];
#pragma unroll
  for (int r = 0; r < 4; ++r) inv[r] = 1.0f / rs[r];
#pragma unroll
  for (int ni = 0; ni < 4; ++ni)
#pragma unroll
    for (int r = 0; r < 4; ++r) {
      const size_t off =
          (bS + q0 + wid * 16 + crow4 + r) * 512 + h * 64 + ni * 16 + ccol;
      ctx[off] = f2bf(cacc[ni][r] * inv[r]);
    }
}

extern "C" void kernel_launch(void* const* d_in, const int* in_sizes, int n_in,
                              void* d_out, int out_size, void* d_ws, size_t ws_size,
                              hipStream_t stream) {
  const float* x = (const float*)d_in[0];
  const float* w_in = (const float*)d_in[1];
  const float* b_in = (const float*)d_in[2];
  const float* w_out = (const float*)d_in[3];
  const float* b_out = (const float*)d_in[4];
  float* out = (float*)d_out;

  const int B = 2, S = 4096, D = 512;
  const int BS = B * S;  // 8192

  char* ws = (char*)d_ws;
  unsigned short* xb = (unsigned short*)(ws + 0);          //  8,388,608
  unsigned short* wbin = (unsigned short*)(ws + 8388608);  //  1,572,864
  unsigned short* wbo = (unsigned short*)(ws + 9961472);   //    524,288
  unsigned short* qkvb = (unsigned short*)(ws + 10485760); // 25,165,824
  unsigned short* ctxb = (unsigned short*)(ws + 35651584); //  8,388,608

  // all fp32->bf16 converts in one launch
  cvt_all<<<2048, 256, 0, stream>>>(x, w_in, w_out, xb, wbin, wbo);

  // QKV projection: 8-phase 256x256, 8 waves -> bf16 [8192,1536]
  gemm8p<<<dim3(6, 32), 512, 0, stream>>>(xb, wbin, b_in, qkvb, BS, 3 * D, D);

  // local attention -> ctx bf16 [8192,512]
  attn_local<<<dim3(S / 64, 16), 256, 0, stream>>>(qkvb, ctxb, S);

  // out projection: [8192,512] x [512,512]^T -> fp32 d_out
  gemm_bt<64, 128, 32, 64>
      <<<dim3(4, 128), 256, 0, stream>>>(ctxb, wbo, b_out, out, BS, D, D);
}

// Round 13
// 55.456 us; speedup vs baseline: 1.0547x; 1.0547x over previous
//
#include <hip/hip_runtime.h>

typedef __attribute__((ext_vector_type(8))) short bf16x8;
typedef __attribute__((ext_vector_type(8))) unsigned short ushort8;
typedef __attribute__((ext_vector_type(4))) float f32x4;

static __device__ __forceinline__ unsigned short f2bf(float f) {
  union { float f; unsigned u; } v; v.f = f;
  unsigned r = v.u + 0x7FFFu + ((v.u >> 16) & 1u);
  return (unsigned short)(r >> 16);
}
static __device__ __forceinline__ int iclamp(int x, int lo, int hi) {
  return x < lo ? lo : (x > hi ? hi : x);
}
// async global->LDS, 16B per lane; LDS dest = wave-uniform base + lane*16
static __device__ __forceinline__ void gl_lds16(const unsigned short* g,
                                                unsigned short* l) {
  __builtin_amdgcn_global_load_lds(
      (const __attribute__((address_space(1))) void*)g,
      (__attribute__((address_space(3))) void*)l, 16, 0, 0);
}

// ---------------- fused fp32 -> bf16 converts (one launch) ----------------
__global__ void cvt_all(const float* __restrict__ x,
                        const float* __restrict__ w_in,
                        const float* __restrict__ w_out,
                        unsigned short* __restrict__ xb,
                        unsigned short* __restrict__ wbin,
                        unsigned short* __restrict__ wbo) {
  const int NX4 = 1048576, NWI4 = 196608, NWO4 = 65536;  // float4 counts
  const int total = NX4 + NWI4 + NWO4;
  for (int i = blockIdx.x * blockDim.x + threadIdx.x; i < total;
       i += gridDim.x * blockDim.x) {
    const float* src;
    unsigned short* dst;
    int o;
    if (i < NX4) {
      src = x; dst = xb; o = i;
    } else if (i < NX4 + NWI4) {
      src = w_in; dst = wbin; o = i - NX4;
    } else {
      src = w_out; dst = wbo; o = i - NX4 - NWI4;
    }
    float4 v = reinterpret_cast<const float4*>(src)[o];
    ushort4 u;
    u.x = f2bf(v.x); u.y = f2bf(v.y); u.z = f2bf(v.z); u.w = f2bf(v.w);
    reinterpret_cast<ushort4*>(dst)[o] = u;
  }
}

// ------- GEMM: C[M][N] = A[M][K](bf16) * B[N][K](bf16)^T + bias -------
// round-6/10 structure: BK=64 double-buffer, gl_lds w16 pre-swizzled source,
// 2-phase pipeline, post-MFMA drain, one barrier per K-step.
// OUT_BF16==1 (requires BM==128): vectorized epilogue -- C tile restaged in
// the free As buffer (32 KB = 128x128 bf16), then 8x coalesced 16B stores.
template <int BM, int BN, int WM, int WN, int OUT_BF16>
__global__ __launch_bounds__(256) void gemm_bt(
    const unsigned short* __restrict__ A, const unsigned short* __restrict__ B,
    const float* __restrict__ bias, void* __restrict__ Cv,
    int M, int N, int K) {
  __shared__ unsigned short As[2][BM][64];
  __shared__ unsigned short Bs[2][BN][64];
  const int tid = threadIdx.x;
  const int lane = tid & 63;
  const int wid = tid >> 6;

  // XCD-aware bijective swizzle (grids here are multiples of 8)
  const int nwg = gridDim.x * gridDim.y;
  const int orig = blockIdx.y * gridDim.x + blockIdx.x;
  const int q = nwg >> 3, r = nwg & 7;
  const int xcd = orig & 7, lid = orig >> 3;
  const int swz = (xcd < r ? xcd * (q + 1) : r * (q + 1) + (xcd - r) * q) + lid;
  const int bm = (swz / gridDim.x) * BM;
  const int bn = (swz % gridDim.x) * BN;

  const int NWC = BN / WN;  // waves along N
  const int wr = (wid / NWC) * WM;
  const int wc = (wid % NWC) * WN;
  const int row16 = lane & 15;
  const int kgrp = lane >> 4;
  const int rsw = row16 & 7;  // read-side swizzle key

  // staging: one gl_lds16 instr = 64 lanes x 16B = 8 rows of 64 elems
  const int srA = wid * (BM / 4) + (lane >> 3);
  const int srB = wid * (BN / 4) + (lane >> 3);
  const int schunk = ((lane & 7) ^ (lane >> 3)) * 8;  // swizzled source col
  const unsigned short* gA = A + (size_t)(bm + srA) * K + schunk;
  const unsigned short* gB = B + (size_t)(bn + srB) * K + schunk;
  const size_t K8 = (size_t)8 * K;

#define STAGE(buf, k0)                                                   \
  {                                                                      \
    _Pragma("unroll") for (int j = 0; j < BM / 32; ++j)                  \
        gl_lds16(gA + j * K8 + (k0), &As[buf][wid * (BM / 4) + j * 8][0]); \
    _Pragma("unroll") for (int j = 0; j < BN / 32; ++j)                  \
        gl_lds16(gB + j * K8 + (k0), &Bs[buf][wid * (BN / 4) + j * 8][0]); \
  }

  f32x4 acc[WM / 16][WN / 16] = {};

  STAGE(0, 0);
  asm volatile("s_waitcnt vmcnt(0)" ::: "memory");
  __builtin_amdgcn_s_barrier();

  const int NT = K >> 6;  // K/64
  for (int t = 0; t < NT; ++t) {
    const int cur = t & 1;
    if (t + 1 < NT) STAGE(cur ^ 1, (t + 1) * 64);
    bf16x8 af[WM / 16][2], bfr[WN / 16][2];
#pragma unroll
    for (int mi = 0; mi < WM / 16; ++mi)
#pragma unroll
      for (int kh = 0; kh < 2; ++kh)
        af[mi][kh] = *reinterpret_cast<const bf16x8*>(
            &As[cur][wr + mi * 16 + row16][((kh * 4 + kgrp) ^ rsw) * 8]);
#pragma unroll
    for (int ni = 0; ni < WN / 16; ++ni)
#pragma unroll
      for (int kh = 0; kh < 2; ++kh)
        bfr[ni][kh] = *reinterpret_cast<const bf16x8*>(
            &Bs[cur][wc + ni * 16 + row16][((kh * 4 + kgrp) ^ rsw) * 8]);
#pragma unroll
    for (int kh = 0; kh < 2; ++kh)
#pragma unroll
      for (int mi = 0; mi < WM / 16; ++mi)
#pragma unroll
        for (int ni = 0; ni < WN / 16; ++ni)
          acc[mi][ni] = __builtin_amdgcn_mfma_f32_16x16x32_bf16(
              af[mi][kh], bfr[ni][kh], acc[mi][ni], 0, 0, 0);
    // drain next-tile loads AFTER compute (latency covered), then barrier
    asm volatile("s_waitcnt vmcnt(0)" ::: "memory");
    __builtin_amdgcn_s_barrier();
  }
#undef STAGE

  if constexpr (OUT_BF16 == 1) {
    // vectorized epilogue: restage C tile (bias applied) in As (now free)
    unsigned short* Cs = &As[0][0][0];  // 128*128 ushorts = 32 KB
#pragma unroll
    for (int ni = 0; ni < WN / 16; ++ni) {
      const float bv = bias[bn + wc + ni * 16 + row16];
#pragma unroll
      for (int mi = 0; mi < WM / 16; ++mi)
#pragma unroll
        for (int r2 = 0; r2 < 4; ++r2)
          Cs[(wr + mi * 16 + kgrp * 4 + r2) * 128 + wc + ni * 16 + row16] =
              f2bf(acc[mi][ni][r2] + bv);
    }
    __syncthreads();
    unsigned short* Cq = reinterpret_cast<unsigned short*>(Cv);
#pragma unroll
    for (int j = 0; j < 8; ++j) {
      const int row = j * 16 + (tid >> 4);
      const int col = (tid & 15) * 8;
      ushort8 v = *reinterpret_cast<const ushort8*>(&Cs[row * 128 + col]);
      *reinterpret_cast<ushort8*>(&Cq[(size_t)(bm + row) * N + bn + col]) = v;
    }
  } else {
#pragma unroll
    for (int ni = 0; ni < WN / 16; ++ni) {
      const int gcol = bn + wc + ni * 16 + row16;
      const float bv = bias[gcol];
#pragma unroll
      for (int mi = 0; mi < WM / 16; ++mi) {
#pragma unroll
        for (int r2 = 0; r2 < 4; ++r2) {
          const int grow = bm + wr + mi * 16 + kgrp * 4 + r2;
          reinterpret_cast<float*>(Cv)[(size_t)grow * N + gcol] =
              acc[mi][ni][r2] + bv;
        }
      }
    }
  }
}

// ---------------- local (banded) attention, v3 + XCD-chunked grid ----------------
// r10 version + vectorized ctx store (restage through wave-private Ps).
__global__ __launch_bounds__(256) void attn_local(
    const unsigned short* __restrict__ qkv, unsigned short* __restrict__ ctx,
    int S) {
  __shared__ unsigned Vt[64][76];            // 19456 B
  __shared__ unsigned short Ps[4][16][104];  // 13312 B

  const int tid = threadIdx.x;
  const int lane = tid & 63;
  const int wid = tid >> 6;

  // bijective XCD-chunked swizzle: nwg = (S/64)*16, multiple of 8
  const int nqb = S >> 6;
  const int nwg = nqb * 16;
  const int orig = blockIdx.y * gridDim.x + blockIdx.x;
  const int cpx = nwg >> 3;
  const int swzb = (orig & 7) * cpx + (orig >> 3);
  const int q0 = (swzb % nqb) * 64;
  const int bh = swzb / nqb;
  const int b = bh >> 3;
  const int h = bh & 7;

  const int row16 = lane & 15;
  const int kgrp = lane >> 4;
  const size_t bS = (size_t)b * S;

  // ---- stage V transposed (packed key pairs) ----
  {
    const int k2 = tid >> 2;
    const int dq = (tid & 3) * 16;
    const int ra = iclamp(q0 - 32 + 2 * k2, 0, S - 1);
    const int rb = iclamp(q0 - 32 + 2 * k2 + 1, 0, S - 1);
    const unsigned short* pa = qkv + (bS + ra) * 1536 + 1024 + h * 64 + dq;
    const unsigned short* pb = qkv + (bS + rb) * 1536 + 1024 + h * 64 + dq;
    ushort8 a0 = reinterpret_cast<const ushort8*>(pa)[0];
    ushort8 a1 = reinterpret_cast<const ushort8*>(pa)[1];
    ushort8 b0 = reinterpret_cast<const ushort8*>(pb)[0];
    ushort8 b1 = reinterpret_cast<const ushort8*>(pb)[1];
#pragma unroll
    for (int d = 0; d < 8; ++d) {
      Vt[dq + d][k2] = (unsigned)a0[d] | ((unsigned)b0[d] << 16);
      Vt[dq + 8 + d][k2] = (unsigned)a1[d] | ((unsigned)b1[d] << 16);
    }
    const int zr = tid >> 2;
    const int zc = 64 + (tid & 3) * 2;
    Vt[zr][zc] = 0u;
    Vt[zr][zc + 1] = 0u;
  }

  // ---- Q fragments (direct from global) ----
  bf16x8 qf0, qf1;
  {
    const unsigned short* qp =
        qkv + (bS + q0 + wid * 16 + row16) * 1536 + h * 64;
    qf0 = *reinterpret_cast<const bf16x8*>(qp + kgrp * 8);
    qf1 = *reinterpret_cast<const bf16x8*>(qp + 32 + kgrp * 8);
  }

  // ---- QK^T: 5 key tiles, K direct from global (clamped rows) ----
  f32x4 sc[5];
#pragma unroll
  for (int t = 0; t < 5; ++t) {
    const int key = iclamp(q0 - 32 + (wid + t) * 16 + row16, 0, S - 1);
    const unsigned short* kp = qkv + (bS + key) * 1536 + 512 + h * 64;
    bf16x8 kf0 = *reinterpret_cast<const bf16x8*>(kp + kgrp * 8);
    bf16x8 kf1 = *reinterpret_cast<const bf16x8*>(kp + 32 + kgrp * 8);
    f32x4 s = {0.f, 0.f, 0.f, 0.f};
    s = __builtin_amdgcn_mfma_f32_16x16x32_bf16(qf0, kf0, s, 0, 0, 0);
    s = __builtin_amdgcn_mfma_f32_16x16x32_bf16(qf1, kf1, s, 0, 0, 0);
    sc[t] = s;
  }

  // ---- mask + softmax ----
  const int ccol = row16;
  const int crow4 = kgrp * 4;
  float rm[4] = {-INFINITY, -INFINITY, -INFINITY, -INFINITY};
#pragma unroll
  for (int t = 0; t < 5; ++t)
#pragma unroll
    for (int r = 0; r < 4; ++r) {
      const int key_abs = q0 - 32 + (wid + t) * 16 + ccol;
      const int diff = -32 + t * 16 + ccol - crow4 - r;
      float s = sc[t][r] * 0.125f;
      const bool valid =
          (diff >= -32) && (diff <= 32) && (key_abs >= 0) && (key_abs < S);
      s = valid ? s : -INFINITY;
      sc[t][r] = s;
      rm[r] = fmaxf(rm[r], s);
    }
#pragma unroll
  for (int off = 1; off < 16; off <<= 1)
#pragma unroll
    for (int r = 0; r < 4; ++r) rm[r] = fmaxf(rm[r], __shfl_xor(rm[r], off, 64));
  float rs[4] = {0.f, 0.f, 0.f, 0.f};
#pragma unroll
  for (int t = 0; t < 5; ++t)
#pragma unroll
    for (int r = 0; r < 4; ++r) {
      const float p = __expf(sc[t][r] - rm[r]);
      sc[t][r] = p;
      rs[r] += p;
    }
#pragma unroll
  for (int off = 1; off < 16; off <<= 1)
#pragma unroll
    for (int r = 0; r < 4; ++r) rs[r] += __shfl_xor(rs[r], off, 64);

  // ---- P -> LDS (bf16), zero-pad keys 80..95 ----
#pragma unroll
  for (int t = 0; t < 5; ++t)
#pragma unroll
    for (int r = 0; r < 4; ++r)
      Ps[wid][crow4 + r][t * 16 + ccol] = f2bf(sc[t][r]);
#pragma unroll
  for (int j = 0; j < 4; ++j) Ps[wid][row16][80 + kgrp * 4 + j] = 0;

  __syncthreads();

  // ---- PV: ctx[16x64] = P[16x96] * V[96x64] ----
  f32x4 cacc[4] = {};
#pragma unroll
  for (int kc = 0; kc < 3; ++kc) {
    bf16x8 pf = *reinterpret_cast<const bf16x8*>(&Ps[wid][row16][kc * 32 + kgrp * 8]);
#pragma unroll
    for (int ni = 0; ni < 4; ++ni) {
      bf16x8 vf = *reinterpret_cast<const bf16x8*>(
          &Vt[ni * 16 + row16][wid * 8 + kc * 16 + kgrp * 4]);
      cacc[ni] = __builtin_amdgcn_mfma_f32_16x16x32_bf16(pf, vf, cacc[ni], 0, 0, 0);
    }
  }

  // ---- normalize; restage tile in wave-private Ps; coalesced store ----
  float inv[4];
#pragma unroll
  for (int r = 0; r < 4; ++r) inv[r] = 1.0f / rs[r];
#pragma unroll
  for (int ni = 0; ni < 4; ++ni)
#pragma unroll
    for (int r = 0; r < 4; ++r)
      Ps[wid][crow4 + r][ni * 16 + ccol] = f2bf(cacc[ni][r] * inv[r]);
  // wave-private buffer: write->read ordered by lgkmcnt (no barrier needed)
#pragma unroll
  for (int j = 0; j < 2; ++j) {
    ushort8 vv = *reinterpret_cast<const ushort8*>(
        &Ps[wid][j * 8 + (lane >> 3)][(lane & 7) * 8]);
    *reinterpret_cast<ushort8*>(
        &ctx[(bS + q0 + wid * 16 + j * 8 + (lane >> 3)) * 512 + h * 64 +
             (lane & 7) * 8]) = vv;
  }
}

extern "C" void kernel_launch(void* const* d_in, const int* in_sizes, int n_in,
                              void* d_out, int out_size, void* d_ws, size_t ws_size,
                              hipStream_t stream) {
  const float* x = (const float*)d_in[0];
  const float* w_in = (const float*)d_in[1];
  const float* b_in = (const float*)d_in[2];
  const float* w_out = (const float*)d_in[3];
  const float* b_out = (const float*)d_in[4];
  float* out = (float*)d_out;

  const int B = 2, S = 4096, D = 512;
  const int BS = B * S;  // 8192

  char* ws = (char*)d_ws;
  unsigned short* xb = (unsigned short*)(ws + 0);          //  8,388,608
  unsigned short* wbin = (unsigned short*)(ws + 8388608);  //  1,572,864
  unsigned short* wbo = (unsigned short*)(ws + 9961472);   //    524,288
  unsigned short* qkvb = (unsigned short*)(ws + 10485760); // 25,165,824
  unsigned short* ctxb = (unsigned short*)(ws + 35651584); //  8,388,608

  // all fp32->bf16 converts in one launch
  cvt_all<<<2048, 256, 0, stream>>>(x, w_in, w_out, xb, wbin, wbo);

  // QKV projection: [8192,512] x [1536,512]^T -> bf16 [8192,1536]
  gemm_bt<128, 128, 64, 64, 1>
      <<<dim3(12, 64), 256, 0, stream>>>(xb, wbin, b_in, qkvb, BS, 3 * D, D);

  // local attention -> ctx bf16 [8192,512]
  attn_local<<<dim3(S / 64, 16), 256, 0, stream>>>(qkvb, ctxb, S);

  // out projection: [8192,512] x [512,512]^T -> fp32 d_out
  gemm_bt<64, 128, 32, 64, 0>
      <<<dim3(4, 128), 256, 0, stream>>>(ctxb, wbo, b_out, out, BS, D, D);
}

// Round 14
// 53.036 us; speedup vs baseline: 1.1028x; 1.0456x over previous
//
#include <hip/hip_runtime.h>

typedef __attribute__((ext_vector_type(8))) short bf16x8;
typedef __attribute__((ext_vector_type(8))) unsigned short ushort8;
typedef __attribute__((ext_vector_type(4))) float f32x4;

static __device__ __forceinline__ unsigned short f2bf(float f) {
  union { float f; unsigned u; } v; v.f = f;
  unsigned r = v.u + 0x7FFFu + ((v.u >> 16) & 1u);
  return (unsigned short)(r >> 16);
}
static __device__ __forceinline__ int iclamp(int x, int lo, int hi) {
  return x < lo ? lo : (x > hi ? hi : x);
}
// async global->LDS, 16B per lane; LDS dest = wave-uniform base + lane*16
static __device__ __forceinline__ void gl_lds16(const unsigned short* g,
                                                unsigned short* l) {
  __builtin_amdgcn_global_load_lds(
      (const __attribute__((address_space(1))) void*)g,
      (__attribute__((address_space(3))) void*)l, 16, 0, 0);
}

// ---------------- fused fp32 -> bf16 converts (one launch) ----------------
__global__ void cvt_all(const float* __restrict__ x,
                        const float* __restrict__ w_in,
                        const float* __restrict__ w_out,
                        unsigned short* __restrict__ xb,
                        unsigned short* __restrict__ wbin,
                        unsigned short* __restrict__ wbo) {
  const int NX4 = 1048576, NWI4 = 196608, NWO4 = 65536;  // float4 counts
  const int total = NX4 + NWI4 + NWO4;
  for (int i = blockIdx.x * blockDim.x + threadIdx.x; i < total;
       i += gridDim.x * blockDim.x) {
    const float* src;
    unsigned short* dst;
    int o;
    if (i < NX4) {
      src = x; dst = xb; o = i;
    } else if (i < NX4 + NWI4) {
      src = w_in; dst = wbin; o = i - NX4;
    } else {
      src = w_out; dst = wbo; o = i - NX4 - NWI4;
    }
    float4 v = reinterpret_cast<const float4*>(src)[o];
    ushort4 u;
    u.x = f2bf(v.x); u.y = f2bf(v.y); u.z = f2bf(v.z); u.w = f2bf(v.w);
    reinterpret_cast<ushort4*>(dst)[o] = u;
  }
}

// ------- GEMM: C[M][N] = A[M][K](bf16) * B[N][K](bf16)^T + bias -------
// 2-phase double-buffer, gl_lds w16 pre-swizzled source, post-MFMA drain,
// one barrier per K-step. BK template param:
//   BK=64: one gl_lds = 8 rows x 64B, swizzle chunk ^= row&7 (r6 mapping)
//   BK=32: one gl_lds = 16 rows x 64B, swizzle chunk ^= row&3 (r7 mapping)
//          -> LDS halved (gemm1: 64->32 KB, 2->4 blocks/CU)
// OUT_BF16==1 (requires BM==128,BN==128): vectorized epilogue via C-restage.
template <int BM, int BN, int WM, int WN, int BK, int OUT_BF16>
__global__ __launch_bounds__(256) void gemm_bt(
    const unsigned short* __restrict__ A, const unsigned short* __restrict__ B,
    const float* __restrict__ bias, void* __restrict__ Cv,
    int M, int N, int K) {
  __shared__ unsigned short As[2][BM][BK];
  __shared__ unsigned short Bs[2][BN][BK];
  const int tid = threadIdx.x;
  const int lane = tid & 63;
  const int wid = tid >> 6;

  // XCD-aware bijective swizzle (grids here are multiples of 8)
  const int nwg = gridDim.x * gridDim.y;
  const int orig = blockIdx.y * gridDim.x + blockIdx.x;
  const int q = nwg >> 3, r = nwg & 7;
  const int xcd = orig & 7, lid = orig >> 3;
  const int swz = (xcd < r ? xcd * (q + 1) : r * (q + 1) + (xcd - r) * q) + lid;
  const int bm = (swz / gridDim.x) * BM;
  const int bn = (swz % gridDim.x) * BN;

  const int NWC = BN / WN;  // waves along N
  const int wr = (wid / NWC) * WM;
  const int wc = (wid % NWC) * WN;
  const int row16 = lane & 15;
  const int kgrp = lane >> 4;
  // read-side swizzle key
  const int rsw = (BK == 64) ? (row16 & 7) : (row16 & 3);

  // staging geometry: one gl_lds16 = 64 lanes x 16B
  //   BK=64: 8 rows (lane>>3), chunk lane&7, src chunk ^= lane>>3
  //   BK=32: 16 rows (lane>>2), chunk lane&3, src chunk ^= (lane>>2)&3
  const int RPI = 1024 / (BK * 2);  // rows per instr: 8 or 16
  const int lrow = (BK == 64) ? (lane >> 3) : (lane >> 2);
  const int lch = (BK == 64) ? ((lane & 7) ^ (lane >> 3))
                             : ((lane & 3) ^ ((lane >> 2) & 3));
  const int srA = wid * (BM / 4) + lrow;
  const int srB = wid * (BN / 4) + lrow;
  const unsigned short* gA = A + (size_t)(bm + srA) * K + lch * 8;
  const unsigned short* gB = B + (size_t)(bn + srB) * K + lch * 8;
  const size_t KR = (size_t)RPI * K;

#define STAGE(buf, k0)                                                     \
  {                                                                        \
    _Pragma("unroll") for (int j = 0; j < BM / (4 * RPI); ++j)             \
        gl_lds16(gA + j * KR + (k0),                                       \
                 &As[buf][wid * (BM / 4) + j * RPI][0]);                   \
    _Pragma("unroll") for (int j = 0; j < BN / (4 * RPI); ++j)             \
        gl_lds16(gB + j * KR + (k0),                                       \
                 &Bs[buf][wid * (BN / 4) + j * RPI][0]);                   \
  }

  f32x4 acc[WM / 16][WN / 16] = {};

  STAGE(0, 0);
  asm volatile("s_waitcnt vmcnt(0)" ::: "memory");
  __builtin_amdgcn_s_barrier();

  const int NT = K / BK;
  for (int t = 0; t < NT; ++t) {
    const int cur = t & 1;
    if (t + 1 < NT) STAGE(cur ^ 1, (t + 1) * BK);
    bf16x8 af[WM / 16][BK / 32], bfr[WN / 16][BK / 32];
#pragma unroll
    for (int mi = 0; mi < WM / 16; ++mi)
#pragma unroll
      for (int kh = 0; kh < BK / 32; ++kh)
        af[mi][kh] = *reinterpret_cast<const bf16x8*>(
            &As[cur][wr + mi * 16 + row16][((kh * 4 + kgrp) ^ rsw) * 8]);
#pragma unroll
    for (int ni = 0; ni < WN / 16; ++ni)
#pragma unroll
      for (int kh = 0; kh < BK / 32; ++kh)
        bfr[ni][kh] = *reinterpret_cast<const bf16x8*>(
            &Bs[cur][wc + ni * 16 + row16][((kh * 4 + kgrp) ^ rsw) * 8]);
#pragma unroll
    for (int kh = 0; kh < BK / 32; ++kh)
#pragma unroll
      for (int mi = 0; mi < WM / 16; ++mi)
#pragma unroll
        for (int ni = 0; ni < WN / 16; ++ni)
          acc[mi][ni] = __builtin_amdgcn_mfma_f32_16x16x32_bf16(
              af[mi][kh], bfr[ni][kh], acc[mi][ni], 0, 0, 0);
    // drain next-tile loads AFTER compute (latency covered), then barrier
    asm volatile("s_waitcnt vmcnt(0)" ::: "memory");
    __builtin_amdgcn_s_barrier();
  }
#undef STAGE

  if constexpr (OUT_BF16 == 1) {
    // vectorized epilogue: restage C tile (bias applied) in As (now free)
    unsigned short* Cs = &As[0][0][0];  // >= 128*128 ushorts
#pragma unroll
    for (int ni = 0; ni < WN / 16; ++ni) {
      const float bv = bias[bn + wc + ni * 16 + row16];
#pragma unroll
      for (int mi = 0; mi < WM / 16; ++mi)
#pragma unroll
        for (int r2 = 0; r2 < 4; ++r2)
          Cs[(wr + mi * 16 + kgrp * 4 + r2) * 128 + wc + ni * 16 + row16] =
              f2bf(acc[mi][ni][r2] + bv);
    }
    __syncthreads();
    unsigned short* Cq = reinterpret_cast<unsigned short*>(Cv);
#pragma unroll
    for (int j = 0; j < 8; ++j) {
      const int row = j * 16 + (tid >> 4);
      const int col = (tid & 15) * 8;
      ushort8 v = *reinterpret_cast<const ushort8*>(&Cs[row * 128 + col]);
      *reinterpret_cast<ushort8*>(&Cq[(size_t)(bm + row) * N + bn + col]) = v;
    }
  } else {
#pragma unroll
    for (int ni = 0; ni < WN / 16; ++ni) {
      const int gcol = bn + wc + ni * 16 + row16;
      const float bv = bias[gcol];
#pragma unroll
      for (int mi = 0; mi < WM / 16; ++mi) {
#pragma unroll
        for (int r2 = 0; r2 < 4; ++r2) {
          const int grow = bm + wr + mi * 16 + kgrp * 4 + r2;
          reinterpret_cast<float*>(Cv)[(size_t)grow * N + gcol] =
              acc[mi][ni][r2] + bv;
        }
      }
    }
  }
}

// ---------------- local (banded) attention, v3 + XCD-chunked grid ----------------
// (r13 version: coalesced ctx store via wave-private Ps restage)
__global__ __launch_bounds__(256) void attn_local(
    const unsigned short* __restrict__ qkv, unsigned short* __restrict__ ctx,
    int S) {
  __shared__ unsigned Vt[64][76];            // 19456 B
  __shared__ unsigned short Ps[4][16][104];  // 13312 B

  const int tid = threadIdx.x;
  const int lane = tid & 63;
  const int wid = tid >> 6;

  // bijective XCD-chunked swizzle: nwg = (S/64)*16, multiple of 8
  const int nqb = S >> 6;
  const int nwg = nqb * 16;
  const int orig = blockIdx.y * gridDim.x + blockIdx.x;
  const int cpx = nwg >> 3;
  const int swzb = (orig & 7) * cpx + (orig >> 3);
  const int q0 = (swzb % nqb) * 64;
  const int bh = swzb / nqb;
  const int b = bh >> 3;
  const int h = bh & 7;

  const int row16 = lane & 15;
  const int kgrp = lane >> 4;
  const size_t bS = (size_t)b * S;

  // ---- stage V transposed (packed key pairs) ----
  {
    const int k2 = tid >> 2;
    const int dq = (tid & 3) * 16;
    const int ra = iclamp(q0 - 32 + 2 * k2, 0, S - 1);
    const int rb = iclamp(q0 - 32 + 2 * k2 + 1, 0, S - 1);
    const unsigned short* pa = qkv + (bS + ra) * 1536 + 1024 + h * 64 + dq;
    const unsigned short* pb = qkv + (bS + rb) * 1536 + 1024 + h * 64 + dq;
    ushort8 a0 = reinterpret_cast<const ushort8*>(pa)[0];
    ushort8 a1 = reinterpret_cast<const ushort8*>(pa)[1];
    ushort8 b0 = reinterpret_cast<const ushort8*>(pb)[0];
    ushort8 b1 = reinterpret_cast<const ushort8*>(pb)[1];
#pragma unroll
    for (int d = 0; d < 8; ++d) {
      Vt[dq + d][k2] = (unsigned)a0[d] | ((unsigned)b0[d] << 16);
      Vt[dq + 8 + d][k2] = (unsigned)a1[d] | ((unsigned)b1[d] << 16);
    }
    const int zr = tid >> 2;
    const int zc = 64 + (tid & 3) * 2;
    Vt[zr][zc] = 0u;
    Vt[zr][zc + 1] = 0u;
  }

  // ---- Q fragments (direct from global) ----
  bf16x8 qf0, qf1;
  {
    const unsigned short* qp =
        qkv + (bS + q0 + wid * 16 + row16) * 1536 + h * 64;
    qf0 = *reinterpret_cast<const bf16x8*>(qp + kgrp * 8);
    qf1 = *reinterpret_cast<const bf16x8*>(qp + 32 + kgrp * 8);
  }

  // ---- QK^T: 5 key tiles, K direct from global (clamped rows) ----
  f32x4 sc[5];
#pragma unroll
  for (int t = 0; t < 5; ++t) {
    const int key = iclamp(q0 - 32 + (wid + t) * 16 + row16, 0, S - 1);
    const unsigned short* kp = qkv + (bS + key) * 1536 + 512 + h * 64;
    bf16x8 kf0 = *reinterpret_cast<const bf16x8*>(kp + kgrp * 8);
    bf16x8 kf1 = *reinterpret_cast<const bf16x8*>(kp + 32 + kgrp * 8);
    f32x4 s = {0.f, 0.f, 0.f, 0.f};
    s = __builtin_amdgcn_mfma_f32_16x16x32_bf16(qf0, kf0, s, 0, 0, 0);
    s = __builtin_amdgcn_mfma_f32_16x16x32_bf16(qf1, kf1, s, 0, 0, 0);
    sc[t] = s;
  }

  // ---- mask + softmax ----
  const int ccol = row16;
  const int crow4 = kgrp * 4;
  float rm[4] = {-INFINITY, -INFINITY, -INFINITY, -INFINITY};
#pragma unroll
  for (int t = 0; t < 5; ++t)
#pragma unroll
    for (int r = 0; r < 4; ++r) {
      const int key_abs = q0 - 32 + (wid + t) * 16 + ccol;
      const int diff = -32 + t * 16 + ccol - crow4 - r;
      float s = sc[t][r] * 0.125f;
      const bool valid =
          (diff >= -32) && (diff <= 32) && (key_abs >= 0) && (key_abs < S);
      s = valid ? s : -INFINITY;
      sc[t][r] = s;
      rm[r] = fmaxf(rm[r], s);
    }
#pragma unroll
  for (int off = 1; off < 16; off <<= 1)
#pragma unroll
    for (int r = 0; r < 4; ++r) rm[r] = fmaxf(rm[r], __shfl_xor(rm[r], off, 64));
  float rs[4] = {0.f, 0.f, 0.f, 0.f};
#pragma unroll
  for (int t = 0; t < 5; ++t)
#pragma unroll
    for (int r = 0; r < 4; ++r) {
      const float p = __expf(sc[t][r] - rm[r]);
      sc[t][r] = p;
      rs[r] += p;
    }
#pragma unroll
  for (int off = 1; off < 16; off <<= 1)
#pragma unroll
    for (int r = 0; r < 4; ++r) rs[r] += __shfl_xor(rs[r], off, 64);

  // ---- P -> LDS (bf16), zero-pad keys 80..95 ----
#pragma unroll
  for (int t = 0; t < 5; ++t)
#pragma unroll
    for (int r = 0; r < 4; ++r)
      Ps[wid][crow4 + r][t * 16 + ccol] = f2bf(sc[t][r]);
#pragma unroll
  for (int j = 0; j < 4; ++j) Ps[wid][row16][80 + kgrp * 4 + j] = 0;

  __syncthreads();

  // ---- PV: ctx[16x64] = P[16x96] * V[96x64] ----
  f32x4 cacc[4] = {};
#pragma unroll
  for (int kc = 0; kc < 3; ++kc) {
    bf16x8 pf = *reinterpret_cast<const bf16x8*>(&Ps[wid][row16][kc * 32 + kgrp * 8]);
#pragma unroll
    for (int ni = 0; ni < 4; ++ni) {
      bf16x8 vf = *reinterpret_cast<const bf16x8*>(
          &Vt[ni * 16 + row16][wid * 8 + kc * 16 + kgrp * 4]);
      cacc[ni] = __builtin_amdgcn_mfma_f32_16x16x32_bf16(pf, vf, cacc[ni], 0, 0, 0);
    }
  }

  // ---- normalize; restage tile in wave-private Ps; coalesced store ----
  float inv[4];
#pragma unroll
  for (int r = 0; r < 4; ++r) inv[r] = 1.0f / rs[r];
#pragma unroll
  for (int ni = 0; ni < 4; ++ni)
#pragma unroll
    for (int r = 0; r < 4; ++r)
      Ps[wid][crow4 + r][ni * 16 + ccol] = f2bf(cacc[ni][r] * inv[r]);
  // wave-private buffer: write->read ordered by lgkmcnt (no barrier needed)
#pragma unroll
  for (int j = 0; j < 2; ++j) {
    ushort8 vv = *reinterpret_cast<const ushort8*>(
        &Ps[wid][j * 8 + (lane >> 3)][(lane & 7) * 8]);
    *reinterpret_cast<ushort8*>(
        &ctx[(bS + q0 + wid * 16 + j * 8 + (lane >> 3)) * 512 + h * 64 +
             (lane & 7) * 8]) = vv;
  }
}

extern "C" void kernel_launch(void* const* d_in, const int* in_sizes, int n_in,
                              void* d_out, int out_size, void* d_ws, size_t ws_size,
                              hipStream_t stream) {
  const float* x = (const float*)d_in[0];
  const float* w_in = (const float*)d_in[1];
  const float* b_in = (const float*)d_in[2];
  const float* w_out = (const float*)d_in[3];
  const float* b_out = (const float*)d_in[4];
  float* out = (float*)d_out;

  const int B = 2, S = 4096, D = 512;
  const int BS = B * S;  // 8192

  char* ws = (char*)d_ws;
  unsigned short* xb = (unsigned short*)(ws + 0);          //  8,388,608
  unsigned short* wbin = (unsigned short*)(ws + 8388608);  //  1,572,864
  unsigned short* wbo = (unsigned short*)(ws + 9961472);   //    524,288
  unsigned short* qkvb = (unsigned short*)(ws + 10485760); // 25,165,824
  unsigned short* ctxb = (unsigned short*)(ws + 35651584); //  8,388,608

  // all fp32->bf16 converts in one launch
  cvt_all<<<2048, 256, 0, stream>>>(x, w_in, w_out, xb, wbin, wbo);

  // QKV projection: [8192,512] x [1536,512]^T -> bf16 [8192,1536]
  // BK=32 dbuf: LDS 32 KB -> ~4 blocks/CU (was 64 KB / 2 blocks at BK=64)
  gemm_bt<128, 128, 64, 64, 32, 1>
      <<<dim3(12, 64), 256, 0, stream>>>(xb, wbin, b_in, qkvb, BS, 3 * D, D);

  // local attention -> ctx bf16 [8192,512]
  attn_local<<<dim3(S / 64, 16), 256, 0, stream>>>(qkvb, ctxb, S);

  // out projection: [8192,512] x [512,512]^T -> fp32 d_out (BK=64 unchanged;
  // grid 512 = 2 blocks/CU is grid-capped, BK change can't raise occupancy)
  gemm_bt<64, 128, 32, 64, 64, 0>
      <<<dim3(4, 128), 256, 0, stream>>>(ctxb, wbo, b_out, out, BS, D, D);
}